// Round 4
// baseline (512.513 us; speedup 1.0000x reference)
//
#include <hip/hip_runtime.h>

// GraphSAGE forward: CSR-gather + bf16x3-split MFMA matmuls (fp32-accurate).
// 3×(SAGEConv + shared Wm/ReLU) -> concat -> global mean pool -> MLP
#define N_NODES 50000
#define N_EDGES 800000
#define D 64
#define N_GRAPHS 512
#define D_TARGET 10
#define NB_SCAN ((N_NODES + 255) / 256)   // 196
#define TPAD 72                            // LDS tile row stride in bf16 (144B = 9*16B)

typedef __attribute__((ext_vector_type(8))) short short8;
typedef __attribute__((ext_vector_type(4))) float f32x4;
#define MFMA16(a, b, c) __builtin_amdgcn_mfma_f32_16x16x32_bf16(a, b, c, 0, 0, 0)

__device__ inline unsigned short bf16rne(float f) {
    unsigned u = __builtin_bit_cast(unsigned, f);
    u += 0x7FFFu + ((u >> 16) & 1u);
    return (unsigned short)(u >> 16);
}
__device__ inline float bf2f(unsigned short h) {
    unsigned u = ((unsigned)h) << 16;
    return __builtin_bit_cast(float, u);
}

// ---- int degree histogram + float graph-count ----
__global__ void count_kernel(const int* __restrict__ dst, const int* __restrict__ batch,
                             int* __restrict__ degi, float* __restrict__ gcnt) {
    int i = blockIdx.x * blockDim.x + threadIdx.x;
    if (i < N_EDGES) atomicAdd(&degi[dst[i]], 1);
    if (i < N_NODES) atomicAdd(&gcnt[batch[i]], 1.0f);
}

__global__ void scan_partials(const int* __restrict__ degi, int* __restrict__ partial) {
    __shared__ int s[256];
    int t = threadIdx.x;
    int i = blockIdx.x * 256 + t;
    s[t] = (i < N_NODES) ? degi[i] : 0;
    __syncthreads();
    for (int off = 128; off > 0; off >>= 1) {
        if (t < off) s[t] += s[t + off];
        __syncthreads();
    }
    if (t == 0) partial[blockIdx.x] = s[0];
}

__global__ void scan_offsets(int* __restrict__ partial) {
    if (threadIdx.x == 0) {
        int run = 0;
        for (int i = 0; i < NB_SCAN; ++i) { int p = partial[i]; partial[i] = run; run += p; }
    }
}

__global__ void scan_final(const int* __restrict__ degi, const int* __restrict__ partial,
                           int* __restrict__ rowptr, int* __restrict__ next) {
    __shared__ int s[256];
    int t = threadIdx.x;
    int i = blockIdx.x * 256 + t;
    int v = (i < N_NODES) ? degi[i] : 0;
    s[t] = v;
    __syncthreads();
    for (int off = 1; off < 256; off <<= 1) {
        int add = (t >= off) ? s[t - off] : 0;
        __syncthreads();
        s[t] += add;
        __syncthreads();
    }
    if (i < N_NODES) {
        int excl = partial[blockIdx.x] + s[t] - v;
        rowptr[i] = excl;
        next[i]   = excl;
    }
    if (i == 0) rowptr[N_NODES] = N_EDGES;
}

__global__ void fill_kernel(const int* __restrict__ src, const int* __restrict__ dst,
                            int* __restrict__ next, int* __restrict__ col) {
    int e = blockIdx.x * blockDim.x + threadIdx.x;
    if (e < N_EDGES) {
        int pos = atomicAdd(&next[dst[e]], 1);
        col[pos] = src[e];
    }
}

// ---- weight prep: fp32 [64][64] -> bf16 hi/lo in MFMA B-fragment order ----
// Per matrix m: out[m*8192 + t] (hi), out[m*8192 + 4096 + t] (lo), where
// t = ((kt*4+nt)*64 + lane)*8 + j maps to W[kt*32 + (lane>>4)*8 + j][nt*16 + (lane&15)].
__global__ void wprep_kernel(const float* __restrict__ w0, const float* __restrict__ w1,
                             const float* __restrict__ w2, const float* __restrict__ w3,
                             const float* __restrict__ w4, const float* __restrict__ w5,
                             const float* __restrict__ w6, short* __restrict__ out) {
    int tid = blockIdx.x * 256 + threadIdx.x;   // 0 .. 7*4096-1
    int m = tid >> 12, t = tid & 4095;
    const float* W = (m == 0) ? w0 : (m == 1) ? w1 : (m == 2) ? w2 : (m == 3) ? w3
                   : (m == 4) ? w4 : (m == 5) ? w5 : w6;
    int j = t & 7, lane = (t >> 3) & 63, nt = (t >> 9) & 3, kt = t >> 11;
    int k = kt * 32 + ((lane >> 4) << 3) + j;
    int o = nt * 16 + (lane & 15);
    float v = W[k * 64 + o];
    unsigned short hi = bf16rne(v);
    unsigned short lo = bf16rne(v - bf2f(hi));
    out[m * 8192 + t]        = (short)hi;
    out[m * 8192 + 4096 + t] = (short)lo;
}

// ---- fused per-layer kernel: one wave per block, 16 nodes per block ----
// Phase 1: CSR gather (4 subgroups x 16 lanes, float4) -> mean & x staged as
//          bf16 hi/lo LDS tiles [16][TPAD].
// Phase 2: t = mean@Wl + bl + x@Wr via bf16x3 MFMA; t -> hi/lo LDS tiles.
// Phase 3: h = relu(t@Wm + bm); write h_out + pool atomics.
__global__ __launch_bounds__(64) void sage_kernel(
    const float* __restrict__ h_in, const int* __restrict__ rowptr, const int* __restrict__ col,
    const short* __restrict__ wl, const short* __restrict__ wr, const short* __restrict__ wm,
    const float* __restrict__ blv, const float* __restrict__ bmv,
    const int* __restrict__ batch,
    float* __restrict__ h_out, float* __restrict__ gsum, int col_off) {
    __shared__ short smh[16 * TPAD];  // mean hi, reused for t hi
    __shared__ short sml[16 * TPAD];  // mean lo, reused for t lo
    __shared__ short sxh[16 * TPAD];  // x hi
    __shared__ short sxl[16 * TPAD];  // x lo

    int lane = threadIdx.x;
    int f = lane & 15;    // float4-chunk / column index
    int g = lane >> 4;    // subgroup 0..3
    int base = blockIdx.x * 16;
    const float4* h4 = (const float4*)h_in;

    // ---- gather ----
    for (int i = 0; i < 16; ++i) {
        int node = base + i;
        int beg = rowptr[node], end = rowptr[node + 1];
        float4 a = make_float4(0.f, 0.f, 0.f, 0.f);
        for (int p = beg + g; p < end; p += 4) {
            int s = col[p];
            float4 v = h4[(size_t)s * 16 + f];
            a.x += v.x; a.y += v.y; a.z += v.z; a.w += v.w;
        }
        a.x += __shfl_xor(a.x, 16); a.y += __shfl_xor(a.y, 16);
        a.z += __shfl_xor(a.z, 16); a.w += __shfl_xor(a.w, 16);
        a.x += __shfl_xor(a.x, 32); a.y += __shfl_xor(a.y, 32);
        a.z += __shfl_xor(a.z, 32); a.w += __shfl_xor(a.w, 32);
        if (g == 0) {
            float inv = 1.0f / fmaxf((float)(end - beg), 1.0f);
            float m0 = a.x * inv, m1 = a.y * inv, m2 = a.z * inv, m3 = a.w * inv;
            unsigned short h0 = bf16rne(m0), h1 = bf16rne(m1), h2 = bf16rne(m2), h3 = bf16rne(m3);
            uint2 hw, lw;
            hw.x = (unsigned)h0 | ((unsigned)h1 << 16);
            hw.y = (unsigned)h2 | ((unsigned)h3 << 16);
            lw.x = (unsigned)bf16rne(m0 - bf2f(h0)) | ((unsigned)bf16rne(m1 - bf2f(h1)) << 16);
            lw.y = (unsigned)bf16rne(m2 - bf2f(h2)) | ((unsigned)bf16rne(m3 - bf2f(h3)) << 16);
            *(uint2*)&smh[i * TPAD + f * 4] = hw;
            *(uint2*)&sml[i * TPAD + f * 4] = lw;
        } else if (g == 1) {
            float4 xv = h4[(size_t)node * 16 + f];
            unsigned short h0 = bf16rne(xv.x), h1 = bf16rne(xv.y), h2 = bf16rne(xv.z), h3 = bf16rne(xv.w);
            uint2 hw, lw;
            hw.x = (unsigned)h0 | ((unsigned)h1 << 16);
            hw.y = (unsigned)h2 | ((unsigned)h3 << 16);
            lw.x = (unsigned)bf16rne(xv.x - bf2f(h0)) | ((unsigned)bf16rne(xv.y - bf2f(h1)) << 16);
            lw.y = (unsigned)bf16rne(xv.z - bf2f(h2)) | ((unsigned)bf16rne(xv.w - bf2f(h3)) << 16);
            *(uint2*)&sxh[i * TPAD + f * 4] = hw;
            *(uint2*)&sxl[i * TPAD + f * 4] = lw;
        }
    }
    // wave-local LDS: same wave produces and consumes; no barrier needed.

    // ---- load A-fragments (row = lane&15, k-chunk = (lane>>4)*8 + kt*32) ----
    short8 amh[2], aml[2], axh[2], axl[2];
#pragma unroll
    for (int kt = 0; kt < 2; ++kt) {
        int idx = f * TPAD + kt * 32 + g * 8;
        amh[kt] = *(const short8*)&smh[idx];
        aml[kt] = *(const short8*)&sml[idx];
        axh[kt] = *(const short8*)&sxh[idx];
        axl[kt] = *(const short8*)&sxl[idx];
    }

    const short* wlh = wl;
    const short* wll = wl + 4096;
    const short* wrh = wr;
    const short* wrl = wr + 4096;

    // ---- mat1: t = mean@Wl + bl + x@Wr (bf16x3) ----
#pragma unroll
    for (int nt = 0; nt < 4; ++nt) {
        f32x4 acc = {0.f, 0.f, 0.f, 0.f};
#pragma unroll
        for (int kt = 0; kt < 2; ++kt) {
            int fi = ((kt * 4 + nt) * 64 + lane) * 8;
            short8 blh = *(const short8*)&wlh[fi];
            short8 bll = *(const short8*)&wll[fi];
            short8 brh = *(const short8*)&wrh[fi];
            short8 brl = *(const short8*)&wrl[fi];
            acc = MFMA16(amh[kt], blh, acc);
            acc = MFMA16(aml[kt], blh, acc);
            acc = MFMA16(amh[kt], bll, acc);
            acc = MFMA16(axh[kt], brh, acc);
            acc = MFMA16(axl[kt], brh, acc);
            acc = MFMA16(axh[kt], brl, acc);
        }
        float bias = blv[nt * 16 + f];
#pragma unroll
        for (int r = 0; r < 4; ++r) {
            float tv = acc[r] + bias;
            unsigned short hi = bf16rne(tv);
            unsigned short lo = bf16rne(tv - bf2f(hi));
            int row = g * 4 + r;   // C layout: row = (lane>>4)*4 + r, col = lane&15
            smh[row * TPAD + nt * 16 + f] = (short)hi;
            sml[row * TPAD + nt * 16 + f] = (short)lo;
        }
    }

    // ---- mat2: h = relu(t@Wm + bm) ----
    short8 ath[2], atl[2];
#pragma unroll
    for (int kt = 0; kt < 2; ++kt) {
        int idx = f * TPAD + kt * 32 + g * 8;
        ath[kt] = *(const short8*)&smh[idx];
        atl[kt] = *(const short8*)&sml[idx];
    }
    const short* wmh = wm;
    const short* wml = wm + 4096;
#pragma unroll
    for (int nt = 0; nt < 4; ++nt) {
        f32x4 acc = {0.f, 0.f, 0.f, 0.f};
#pragma unroll
        for (int kt = 0; kt < 2; ++kt) {
            int fi = ((kt * 4 + nt) * 64 + lane) * 8;
            short8 bh = *(const short8*)&wmh[fi];
            short8 bl2 = *(const short8*)&wml[fi];
            acc = MFMA16(ath[kt], bh, acc);
            acc = MFMA16(atl[kt], bh, acc);
            acc = MFMA16(ath[kt], bl2, acc);
        }
        float bias = bmv[nt * 16 + f];
#pragma unroll
        for (int r = 0; r < 4; ++r) {
            float hv = acc[r] + bias;
            hv = hv > 0.f ? hv : 0.f;
            int row = g * 4 + r;
            int node = base + row;
            h_out[node * D + nt * 16 + f] = hv;
            atomicAdd(&gsum[batch[node] * (3 * D) + col_off + nt * 16 + f], hv);
        }
    }
}

// ---- pooled MLP: g = gsum/cnt; t = relu(g@W1+b1); out = t@W2+b2 ----
__global__ void pool_mlp_kernel(const float* __restrict__ gsum, const float* __restrict__ gcnt,
                                const float* __restrict__ W1, const float* __restrict__ b1,
                                const float* __restrict__ W2, const float* __restrict__ b2,
                                float* __restrict__ out) {
    __shared__ float g[3 * D];
    __shared__ float tt[D];
    int gr = blockIdx.x;
    int t  = threadIdx.x;  // 64 threads
    float cnt = gcnt[gr];
    if (cnt < 1.f) cnt = 1.f;
    for (int i = t; i < 3 * D; i += 64) g[i] = gsum[gr * 3 * D + i] / cnt;
    __syncthreads();

    float acc = b1[t];
#pragma unroll 8
    for (int k = 0; k < 3 * D; ++k) acc += g[k] * W1[k * D + t];
    tt[t] = acc > 0.f ? acc : 0.f;
    __syncthreads();

    if (t < D_TARGET) {
        float acc2 = b2[t];
#pragma unroll
        for (int k = 0; k < D; ++k) acc2 += tt[k] * W2[k * D_TARGET + t];
        out[gr * D_TARGET + t] = acc2;
    }
}

extern "C" void kernel_launch(void* const* d_in, const int* in_sizes, int n_in,
                              void* d_out, int out_size, void* d_ws, size_t ws_size,
                              hipStream_t stream) {
    const float* x     = (const float*)d_in[0];
    const int*   ei    = (const int*)d_in[1];
    const int*   src   = ei;
    const int*   dst   = ei + N_EDGES;
    const int*   batch = (const int*)d_in[2];

    const float* Wl[3] = {(const float*)d_in[3], (const float*)d_in[6], (const float*)d_in[9]};
    const float* bl[3] = {(const float*)d_in[4], (const float*)d_in[7], (const float*)d_in[10]};
    const float* Wr[3] = {(const float*)d_in[5], (const float*)d_in[8], (const float*)d_in[11]};
    const float* Wm = (const float*)d_in[12];
    const float* bm = (const float*)d_in[13];
    const float* W1 = (const float*)d_in[14];
    const float* b1 = (const float*)d_in[15];
    const float* W2 = (const float*)d_in[16];
    const float* b2 = (const float*)d_in[17];

    // workspace layout (4-byte words)
    int*   degi    = (int*)d_ws;                       // 50000
    float* gsum    = (float*)(degi + N_NODES);         // 98304
    float* gcnt    = gsum + N_GRAPHS * 3 * D;          // 512
    int*   partial = (int*)(gcnt + N_GRAPHS);          // 256
    int*   rowptr  = partial + 256;                    // 50001
    int*   next    = rowptr + N_NODES + 1;             // 50000
    int*   col     = next + N_NODES;                   // 800000
    short* wfrag   = (short*)(col + N_EDGES + 3);      // +3 pad -> 16B aligned; 7*8192 shorts
    float* hA      = (float*)(wfrag + 7 * 8192);       // 3,200,000
    float* hB      = hA + (size_t)N_NODES * D;         // 3,200,000

    // zero degi + gsum + gcnt (contiguous)
    hipMemsetAsync(degi, 0, (N_NODES + N_GRAPHS * 3 * D + N_GRAPHS) * sizeof(float), stream);

    count_kernel<<<(N_EDGES + 255) / 256, 256, 0, stream>>>(dst, batch, degi, gcnt);
    scan_partials<<<NB_SCAN, 256, 0, stream>>>(degi, partial);
    scan_offsets<<<1, 64, 0, stream>>>(partial);
    scan_final<<<NB_SCAN, 256, 0, stream>>>(degi, partial, rowptr, next);
    fill_kernel<<<(N_EDGES + 255) / 256, 256, 0, stream>>>(src, dst, next, col);
    // weight prep: Wl0,Wr0,Wl1,Wr1,Wl2,Wr2,Wm -> bf16 hi/lo fragment order
    wprep_kernel<<<7 * 4096 / 256, 256, 0, stream>>>(
        Wl[0], Wr[0], Wl[1], Wr[1], Wl[2], Wr[2], Wm, wfrag);

    const float* hin = x;
    float* hout = hA;
    for (int l = 0; l < 3; ++l) {
        sage_kernel<<<N_NODES / 16, 64, 0, stream>>>(
            hin, rowptr, col,
            wfrag + (2 * l) * 8192, wfrag + (2 * l + 1) * 8192, wfrag + 6 * 8192,
            bl[l], bm, batch, hout, gsum, l * D);
        hin  = hout;
        hout = (hout == hA) ? hB : hA;
    }

    pool_mlp_kernel<<<N_GRAPHS, 64, 0, stream>>>(gsum, gcnt, W1, b1, W2, b2, (float*)d_out);
}

// Round 6
// 476.356 us; speedup vs baseline: 1.0759x; 1.0759x over previous
//
#include <hip/hip_runtime.h>

// GraphSAGE forward: CSR gather (wave-per-node, 16 waves/block) + bf16x3 MFMA matmuls.
// 3×(SAGEConv + shared Wm/ReLU) -> concat -> global mean pool -> MLP
#define N_NODES 50000
#define N_EDGES 800000
#define D 64
#define N_GRAPHS 512
#define D_TARGET 10
#define NB_SCAN ((N_NODES + 255) / 256)   // 196
#define TPAD 72                            // LDS tile row stride in bf16

typedef __attribute__((ext_vector_type(8))) short short8;
typedef __attribute__((ext_vector_type(4))) float f32x4;
#define MFMA16(a, b, c) __builtin_amdgcn_mfma_f32_16x16x32_bf16(a, b, c, 0, 0, 0)

__device__ inline unsigned short bf16rne(float f) {
    unsigned u = __builtin_bit_cast(unsigned, f);
    u += 0x7FFFu + ((u >> 16) & 1u);
    return (unsigned short)(u >> 16);
}
__device__ inline float bf2f(unsigned short h) {
    unsigned u = ((unsigned)h) << 16;
    return __builtin_bit_cast(float, u);
}

// ---- int degree histogram + float graph-count ----
__global__ void count_kernel(const int* __restrict__ dst, const int* __restrict__ batch,
                             int* __restrict__ degi, float* __restrict__ gcnt) {
    int i = blockIdx.x * blockDim.x + threadIdx.x;
    if (i < N_EDGES) atomicAdd(&degi[dst[i]], 1);
    if (i < N_NODES) atomicAdd(&gcnt[batch[i]], 1.0f);
}

__global__ void scan_partials(const int* __restrict__ degi, int* __restrict__ partial) {
    __shared__ int s[256];
    int t = threadIdx.x;
    int i = blockIdx.x * 256 + t;
    s[t] = (i < N_NODES) ? degi[i] : 0;
    __syncthreads();
    for (int off = 128; off > 0; off >>= 1) {
        if (t < off) s[t] += s[t + off];
        __syncthreads();
    }
    if (t == 0) partial[blockIdx.x] = s[0];
}

__global__ void scan_offsets(int* __restrict__ partial) {
    if (threadIdx.x == 0) {
        int run = 0;
        for (int i = 0; i < NB_SCAN; ++i) { int p = partial[i]; partial[i] = run; run += p; }
    }
}

__global__ void scan_final(const int* __restrict__ degi, const int* __restrict__ partial,
                           int* __restrict__ rowptr, int* __restrict__ next) {
    __shared__ int s[256];
    int t = threadIdx.x;
    int i = blockIdx.x * 256 + t;
    int v = (i < N_NODES) ? degi[i] : 0;
    s[t] = v;
    __syncthreads();
    for (int off = 1; off < 256; off <<= 1) {
        int add = (t >= off) ? s[t - off] : 0;
        __syncthreads();
        s[t] += add;
        __syncthreads();
    }
    if (i < N_NODES) {
        int excl = partial[blockIdx.x] + s[t] - v;
        rowptr[i] = excl;
        next[i]   = excl;
    }
    if (i == 0) rowptr[N_NODES] = N_EDGES;
}

__global__ void fill_kernel(const int* __restrict__ src, const int* __restrict__ dst,
                            int* __restrict__ next, int* __restrict__ col) {
    int e = blockIdx.x * blockDim.x + threadIdx.x;
    if (e < N_EDGES) {
        int pos = atomicAdd(&next[dst[e]], 1);
        col[pos] = src[e];
    }
}

// ---- weight prep: fp32 [64][64] -> bf16 hi/lo in MFMA B-fragment order ----
__global__ void wprep_kernel(const float* __restrict__ w0, const float* __restrict__ w1,
                             const float* __restrict__ w2, const float* __restrict__ w3,
                             const float* __restrict__ w4, const float* __restrict__ w5,
                             const float* __restrict__ w6, short* __restrict__ out) {
    int tid = blockIdx.x * 256 + threadIdx.x;   // 0 .. 7*4096-1
    int m = tid >> 12, t = tid & 4095;
    const float* W = (m == 0) ? w0 : (m == 1) ? w1 : (m == 2) ? w2 : (m == 3) ? w3
                   : (m == 4) ? w4 : (m == 5) ? w5 : w6;
    int j = t & 7, lane = (t >> 3) & 63, nt = (t >> 9) & 3, kt = t >> 11;
    int k = kt * 32 + ((lane >> 4) << 3) + j;
    int o = nt * 16 + (lane & 15);
    float v = W[k * 64 + o];
    unsigned short hi = bf16rne(v);
    unsigned short lo = bf16rne(v - bf2f(hi));
    out[m * 8192 + t]        = (short)hi;
    out[m * 8192 + 4096 + t] = (short)lo;
}

// ---- fused per-layer kernel: 16 waves/block; wave w gathers node base+w;
//      waves 0..3 then do the 16x64 matmuls (bf16x3 MFMA, nt = wave id). ----
__global__ __launch_bounds__(1024) void sage_kernel(
    const float* __restrict__ h_in, const int* __restrict__ rowptr, const int* __restrict__ col,
    const short* __restrict__ wl, const short* __restrict__ wr, const short* __restrict__ wm,
    const float* __restrict__ blv, const float* __restrict__ bmv,
    const int* __restrict__ batch,
    float* __restrict__ h_out, float* __restrict__ gsum, int col_off) {
    __shared__ short smh[16 * TPAD];  // mean hi
    __shared__ short sml[16 * TPAD];  // mean lo
    __shared__ short sxh[16 * TPAD];  // x hi
    __shared__ short sxl[16 * TPAD];  // x lo
    __shared__ short sth[16 * TPAD];  // t hi
    __shared__ short stl[16 * TPAD];  // t lo

    int tid  = threadIdx.x;
    int wid  = tid >> 6;
    int lane = tid & 63;
    int f    = lane & 15;   // float4-chunk / column index
    int g    = lane >> 4;   // subgroup 0..3
    int base = blockIdx.x * 16;
    const float4* h4 = (const float4*)h_in;

    // ---- gather: wave `wid` handles node base+wid ----
    {
        int node = base + wid;
        int beg = rowptr[node], end = rowptr[node + 1];
        float4 xv = make_float4(0.f, 0.f, 0.f, 0.f);
        if (g == 1) xv = h4[node * 16 + f];   // issue root load early
        float4 a0 = make_float4(0.f, 0.f, 0.f, 0.f);
        float4 a1 = make_float4(0.f, 0.f, 0.f, 0.f);
        int p = beg + g;
        for (; p + 4 < end; p += 8) {
            int s0 = col[p];
            int s1 = col[p + 4];
            float4 v0 = h4[s0 * 16 + f];
            float4 v1 = h4[s1 * 16 + f];
            a0.x += v0.x; a0.y += v0.y; a0.z += v0.z; a0.w += v0.w;
            a1.x += v1.x; a1.y += v1.y; a1.z += v1.z; a1.w += v1.w;
        }
        if (p < end) {
            float4 v = h4[col[p] * 16 + f];
            a0.x += v.x; a0.y += v.y; a0.z += v.z; a0.w += v.w;
        }
        a0.x += a1.x; a0.y += a1.y; a0.z += a1.z; a0.w += a1.w;
        a0.x += __shfl_xor(a0.x, 16); a0.y += __shfl_xor(a0.y, 16);
        a0.z += __shfl_xor(a0.z, 16); a0.w += __shfl_xor(a0.w, 16);
        a0.x += __shfl_xor(a0.x, 32); a0.y += __shfl_xor(a0.y, 32);
        a0.z += __shfl_xor(a0.z, 32); a0.w += __shfl_xor(a0.w, 32);
        if (g == 0) {
            float inv = 1.0f / fmaxf((float)(end - beg), 1.0f);
            float m0 = a0.x * inv, m1 = a0.y * inv, m2 = a0.z * inv, m3 = a0.w * inv;
            unsigned short h0 = bf16rne(m0), h1 = bf16rne(m1), h2 = bf16rne(m2), h3 = bf16rne(m3);
            uint2 hw, lw;
            hw.x = (unsigned)h0 | ((unsigned)h1 << 16);
            hw.y = (unsigned)h2 | ((unsigned)h3 << 16);
            lw.x = (unsigned)bf16rne(m0 - bf2f(h0)) | ((unsigned)bf16rne(m1 - bf2f(h1)) << 16);
            lw.y = (unsigned)bf16rne(m2 - bf2f(h2)) | ((unsigned)bf16rne(m3 - bf2f(h3)) << 16);
            *(uint2*)&smh[wid * TPAD + f * 4] = hw;
            *(uint2*)&sml[wid * TPAD + f * 4] = lw;
        } else if (g == 1) {
            unsigned short h0 = bf16rne(xv.x), h1 = bf16rne(xv.y), h2 = bf16rne(xv.z), h3 = bf16rne(xv.w);
            uint2 hw, lw;
            hw.x = (unsigned)h0 | ((unsigned)h1 << 16);
            hw.y = (unsigned)h2 | ((unsigned)h3 << 16);
            lw.x = (unsigned)bf16rne(xv.x - bf2f(h0)) | ((unsigned)bf16rne(xv.y - bf2f(h1)) << 16);
            lw.y = (unsigned)bf16rne(xv.z - bf2f(h2)) | ((unsigned)bf16rne(xv.w - bf2f(h3)) << 16);
            *(uint2*)&sxh[wid * TPAD + f * 4] = hw;
            *(uint2*)&sxl[wid * TPAD + f * 4] = lw;
        }
    }
    __syncthreads();

    // ---- mat1: t = mean@Wl + bl + x@Wr (waves 0..3, nt = wid) ----
    if (wid < 4) {
        int nt = wid;
        short8 amh[2], aml[2], axh[2], axl[2];
#pragma unroll
        for (int kt = 0; kt < 2; ++kt) {
            int idx = f * TPAD + kt * 32 + g * 8;
            amh[kt] = *(const short8*)&smh[idx];
            aml[kt] = *(const short8*)&sml[idx];
            axh[kt] = *(const short8*)&sxh[idx];
            axl[kt] = *(const short8*)&sxl[idx];
        }
        const short* wlh = wl;
        const short* wll = wl + 4096;
        const short* wrh = wr;
        const short* wrl = wr + 4096;
        f32x4 acc = {0.f, 0.f, 0.f, 0.f};
#pragma unroll
        for (int kt = 0; kt < 2; ++kt) {
            int fi = ((kt * 4 + nt) * 64 + lane) * 8;
            short8 blh = *(const short8*)&wlh[fi];
            short8 bll = *(const short8*)&wll[fi];
            short8 brh = *(const short8*)&wrh[fi];
            short8 brl = *(const short8*)&wrl[fi];
            acc = MFMA16(amh[kt], blh, acc);
            acc = MFMA16(aml[kt], blh, acc);
            acc = MFMA16(amh[kt], bll, acc);
            acc = MFMA16(axh[kt], brh, acc);
            acc = MFMA16(axl[kt], brh, acc);
            acc = MFMA16(axh[kt], brl, acc);
        }
        float bias = blv[nt * 16 + f];
#pragma unroll
        for (int r = 0; r < 4; ++r) {
            float tv = acc[r] + bias;
            unsigned short hi = bf16rne(tv);
            unsigned short lo = bf16rne(tv - bf2f(hi));
            int row = g * 4 + r;   // C layout: row=(lane>>4)*4+r, col=lane&15
            sth[row * TPAD + nt * 16 + f] = (short)hi;
            stl[row * TPAD + nt * 16 + f] = (short)lo;
        }
    }
    __syncthreads();

    // ---- mat2: h = relu(t@Wm + bm) (waves 0..3, nt = wid) ----
    if (wid < 4) {
        int nt = wid;
        short8 ath[2], atl[2];
#pragma unroll
        for (int kt = 0; kt < 2; ++kt) {
            int idx = f * TPAD + kt * 32 + g * 8;
            ath[kt] = *(const short8*)&sth[idx];
            atl[kt] = *(const short8*)&stl[idx];
        }
        const short* wmh = wm;
        const short* wml = wm + 4096;
        f32x4 acc = {0.f, 0.f, 0.f, 0.f};
#pragma unroll
        for (int kt = 0; kt < 2; ++kt) {
            int fi = ((kt * 4 + nt) * 64 + lane) * 8;
            short8 bh  = *(const short8*)&wmh[fi];
            short8 bl2 = *(const short8*)&wml[fi];
            acc = MFMA16(ath[kt], bh, acc);
            acc = MFMA16(atl[kt], bh, acc);
            acc = MFMA16(ath[kt], bl2, acc);
        }
        float bias = bmv[nt * 16 + f];
#pragma unroll
        for (int r = 0; r < 4; ++r) {
            float hv = acc[r] + bias;
            hv = hv > 0.f ? hv : 0.f;
            int row  = g * 4 + r;
            int node = base + row;
            h_out[node * D + nt * 16 + f] = hv;
            atomicAdd(&gsum[batch[node] * (3 * D) + col_off + nt * 16 + f], hv);
        }
    }
}

// ---- pooled MLP: g = gsum/cnt; t = relu(g@W1+b1); out = t@W2+b2 ----
__global__ void pool_mlp_kernel(const float* __restrict__ gsum, const float* __restrict__ gcnt,
                                const float* __restrict__ W1, const float* __restrict__ b1,
                                const float* __restrict__ W2, const float* __restrict__ b2,
                                float* __restrict__ out) {
    __shared__ float g[3 * D];
    __shared__ float tt[D];
    int gr = blockIdx.x;
    int t  = threadIdx.x;  // 64 threads
    float cnt = gcnt[gr];
    if (cnt < 1.f) cnt = 1.f;
    for (int i = t; i < 3 * D; i += 64) g[i] = gsum[gr * 3 * D + i] / cnt;
    __syncthreads();

    float acc = b1[t];
#pragma unroll 8
    for (int k = 0; k < 3 * D; ++k) acc += g[k] * W1[k * D + t];
    tt[t] = acc > 0.f ? acc : 0.f;
    __syncthreads();

    if (t < D_TARGET) {
        float acc2 = b2[t];
#pragma unroll
        for (int k = 0; k < D; ++k) acc2 += tt[k] * W2[k * D_TARGET + t];
        out[gr * D_TARGET + t] = acc2;
    }
}

extern "C" void kernel_launch(void* const* d_in, const int* in_sizes, int n_in,
                              void* d_out, int out_size, void* d_ws, size_t ws_size,
                              hipStream_t stream) {
    const float* x     = (const float*)d_in[0];
    const int*   ei    = (const int*)d_in[1];
    const int*   src   = ei;
    const int*   dst   = ei + N_EDGES;
    const int*   batch = (const int*)d_in[2];

    const float* Wl[3] = {(const float*)d_in[3], (const float*)d_in[6], (const float*)d_in[9]};
    const float* bl[3] = {(const float*)d_in[4], (const float*)d_in[7], (const float*)d_in[10]};
    const float* Wr[3] = {(const float*)d_in[5], (const float*)d_in[8], (const float*)d_in[11]};
    const float* Wm = (const float*)d_in[12];
    const float* bm = (const float*)d_in[13];
    const float* W1 = (const float*)d_in[14];
    const float* b1 = (const float*)d_in[15];
    const float* W2 = (const float*)d_in[16];
    const float* b2 = (const float*)d_in[17];

    // workspace layout (4-byte words)
    int*   degi    = (int*)d_ws;                       // 50000
    float* gsum    = (float*)(degi + N_NODES);         // 98304
    float* gcnt    = gsum + N_GRAPHS * 3 * D;          // 512
    int*   partial = (int*)(gcnt + N_GRAPHS);          // 256
    int*   rowptr  = partial + 256;                    // 50001
    int*   next    = rowptr + N_NODES + 1;             // 50000
    int*   col     = next + N_NODES;                   // 800000
    short* wfrag   = (short*)(col + N_EDGES + 3);      // 16B aligned; 7*8192 shorts
    float* hA      = (float*)(wfrag + 7 * 8192);       // 3,200,000
    float* hB      = hA + (size_t)N_NODES * D;         // 3,200,000

    // zero degi + gsum + gcnt (contiguous)
    hipMemsetAsync(degi, 0, (N_NODES + N_GRAPHS * 3 * D + N_GRAPHS) * sizeof(float), stream);

    count_kernel<<<(N_EDGES + 255) / 256, 256, 0, stream>>>(dst, batch, degi, gcnt);
    scan_partials<<<NB_SCAN, 256, 0, stream>>>(degi, partial);
    scan_offsets<<<1, 64, 0, stream>>>(partial);
    scan_final<<<NB_SCAN, 256, 0, stream>>>(degi, partial, rowptr, next);
    fill_kernel<<<(N_EDGES + 255) / 256, 256, 0, stream>>>(src, dst, next, col);
    wprep_kernel<<<7 * 4096 / 256, 256, 0, stream>>>(
        Wl[0], Wr[0], Wl[1], Wr[1], Wl[2], Wr[2], Wm, wfrag);

    const float* hin = x;
    float* hout = hA;
    for (int l = 0; l < 3; ++l) {
        sage_kernel<<<N_NODES / 16, 1024, 0, stream>>>(
            hin, rowptr, col,
            wfrag + (2 * l) * 8192, wfrag + (2 * l + 1) * 8192, wfrag + 6 * 8192,
            bl[l], bm, batch, hout, gsum, l * D);
        hin  = hout;
        hout = (hout == hA) ? hB : hA;
    }

    pool_mlp_kernel<<<N_GRAPHS, 64, 0, stream>>>(gsum, gcnt, W1, b1, W2, b2, (float*)d_out);
}